// Round 27
// baseline (77.268 us; speedup 1.0000x reference)
//
#include <hip/hip_runtime.h>
#include <hip/hip_fp16.h>

#define TPB 256
constexpr int B_ = 8, C_ = 192, H_ = 56, W_ = 56, O_ = 384;
constexpr int HW_ = H_ * W_;          // 3136
constexpr int NOFF = 18;              // 9 taps * 2 (dy,dx)
constexpr int NPIX = B_ * HW_;        // 25088
constexpr int K2 = 9 * C_;            // 1728 combined-conv K

typedef __attribute__((ext_vector_type(8))) short short8v;
typedef __attribute__((ext_vector_type(4))) float f32x4;
typedef __attribute__((ext_vector_type(2))) float f32x2;

__device__ inline unsigned short f2bf(float f) {
  unsigned u = __builtin_bit_cast(unsigned, f);
  unsigned r = (u + 0x7fffu + ((u >> 16) & 1u)) >> 16;
  return (unsigned short)r;
}
__device__ inline float bflo(unsigned u) {
  return __builtin_bit_cast(float, u << 16);
}
__device__ inline float bfhi(unsigned u) {
  return __builtin_bit_cast(float, u & 0xffff0000u);
}

// ---- K_XTP: x transpose->bf16 AND all weight prep in one launch ----------
__global__ __launch_bounds__(TPB) void k_xtp(const float* __restrict__ x,
                                             const float* __restrict__ og_dw,
                                             const float* __restrict__ og_pw,
                                             const float* __restrict__ pw,
                                             const float* __restrict__ dcn,
                                             unsigned short* __restrict__ xt,
                                             unsigned short* __restrict__ wtb,
                                             unsigned short* __restrict__ w2b,
                                             float* __restrict__ dcnT_g) {
  __shared__ unsigned short tile[64 * 198];
  int tid = threadIdx.x;
  int P0 = blockIdx.x * 64;
  int b = blockIdx.y;

  int gid = (blockIdx.y * 49 + blockIdx.x) * TPB + tid;
#pragma unroll
  for (int it = 0; it < 2; ++it) {
    int i = gid + it * (49 * 8 * TPB);
    if (i < O_ * C_) {
      wtb[i] = f2bf(pw[i]);
    } else if (i < O_ * C_ + 32 * K2) {
      int j = i - O_ * C_;
      int o = j / K2, k = j - o * K2;
      int tap = k / C_, c = k - tap * C_;
      float v = 0.f;
      if (o < NOFF) v = og_pw[o * C_ + c] * og_dw[c * 9 + tap];
      w2b[j] = f2bf(v);
    } else if (i < O_ * C_ + 32 * K2 + 9 * C_) {
      int j2 = i - O_ * C_ - 32 * K2;
      int k = j2 / C_, c = j2 - k * C_;
      dcnT_g[j2] = dcn[c * 9 + k];
    }
  }

#pragma unroll
  for (int i = 0; i < 48; ++i) {
    int idx = i * TPB + tid;
    int px = idx & 63;
    int c = idx >> 6;
    float v = x[((size_t)(b * C_ + c)) * HW_ + P0 + px];
    tile[px * 198 + c] = f2bf(v);
  }
  __syncthreads();
  unsigned* xtu = (unsigned*)xt;
#pragma unroll
  for (int i = 0; i < 24; ++i) {
    int d = i * TPB + tid;
    int px = d / 96;
    int c2 = d - px * 96;
    unsigned v = *(const unsigned*)&tile[px * 198 + c2 * 2];
    xtu[((size_t)b * HW_ + P0 + px) * 96 + c2] = v;
  }
}

// ---- K_OFF2s: offset conv, K-split by tap-row; batch->XCD swizzled -------
__global__ __launch_bounds__(TPB) void k_off2s(const unsigned short* __restrict__ xt,
                                               const unsigned short* __restrict__ w2b,
                                               float* __restrict__ offp3) {
  __shared__ __align__(16) unsigned short hal[80 * 192];  // 30.7 KB
  int tid = threadIdx.x;
  int w0 = blockIdx.x * 8;
  int h0 = blockIdx.y * 8;
  int bz = blockIdx.z;
  int b = bz & 7;
  int s = bz >> 3;
  int dy = s - 1;

  char* sb = (char*)hal;
  const uint4* xu4 = (const uint4*)xt;
#pragma unroll
  for (int i = 0; i < 8; ++i) {
    int u = i * TPB + tid;
    if (u < 1920) {
      int pos = u / 24, c4 = u - pos * 24;
      int ry = pos / 10;
      int gy = h0 + ry + dy;
      int gx = w0 - 1 + (pos - ry * 10);
      uint4 v = {0u, 0u, 0u, 0u};
      if ((unsigned)gy < (unsigned)H_ && (unsigned)gx < (unsigned)W_)
        v = xu4[((size_t)b * HW_ + gy * W_ + gx) * 24 + c4];
      *(uint4*)(sb + pos * 384 + ((c4 * 16) ^ ((pos & 7) << 4))) = v;
    }
  }
  __syncthreads();

  int wid = tid >> 6;
  int lane = tid & 63;
  int col = lane & 15;
  int kg = lane >> 4;
  int gpx = wid * 16 + col;
  int py = gpx >> 3, px_ = gpx & 7;

  f32x4 acc0 = (f32x4){0.f, 0.f, 0.f, 0.f};
  f32x4 acc1 = (f32x4){0.f, 0.f, 0.f, 0.f};

#pragma unroll
  for (int j = 0; j < 3; ++j) {
    int tap = 3 * s + j;
    int pos = py * 10 + px_ + j;
    int pbase = pos * 384;
    int psw = (pos & 7) << 4;
    const unsigned short* wrow = w2b + tap * C_ + kg * 8;
#pragma unroll
    for (int cs = 0; cs < 6; ++cs) {
      short8v bfrag = *(const short8v*)(sb + pbase + ((cs * 64 + kg * 16) ^ psw));
      short8v a0 = *(const short8v*)(wrow + cs * 32 + (size_t)col * K2);
      short8v a1 = *(const short8v*)(wrow + cs * 32 + (size_t)(16 + col) * K2);
      acc0 = __builtin_amdgcn_mfma_f32_16x16x32_bf16(a0, bfrag, acc0, 0, 0, 0);
      acc1 = __builtin_amdgcn_mfma_f32_16x16x32_bf16(a1, bfrag, acc1, 0, 0, 0);
    }
  }

  float* ob = offp3 + (size_t)(s * B_ + b) * NOFF * HW_ + (h0 + py) * W_ + w0 + px_;
#pragma unroll
  for (int reg = 0; reg < 4; ++reg) {
    int o0 = kg * 4 + reg;
    ob[(size_t)o0 * HW_] = acc0[reg];
    int o1 = 16 + kg * 4 + reg;
    if (o1 < NOFF) ob[(size_t)o1 * HW_] = acc1[reg];
  }
}

// ---- K_DFG4: fused deform+gemm; weights hoisted pre-sync + shfl bcast ----
// Weight phase's global loads overlap halo staging (both before first
// barrier); w4tab/postab LDS deleted (44.9 KB total); one barrier removed.
__global__ __launch_bounds__(512, 4) void k_dfg4(const unsigned short* __restrict__ xt,
                                                 const float* __restrict__ offp3,
                                                 const float* __restrict__ dcnT_g,
                                                 const unsigned short* __restrict__ wtb,
                                                 float* __restrict__ out) {
  __shared__ __align__(16) unsigned short hal[117 * 192];  // 44.9 KB; bsm aliases first 12 KB
  int tid = threadIdx.x;
  int bid = blockIdx.x;
  int b = bid & 7;                    // XCD-locality: batch b -> XCD b
  int tile = bid >> 3;                // 0..97
  int ty = tile / 7;
  int h0 = ty * 4;
  int w0 = (tile - ty * 7) * 8;

  int pl = tid >> 4;                  // 0..31: local pixel
  int lg = tid & 15;
  int co0 = lg * 4;

  // ---- per-lane weight precompute (lanes lg<9 of each pixel group); the
  // global offp3 loads drain concurrently with halo staging below ----
  float myw0 = 0.f, myw1 = 0.f, myw2 = 0.f, myw3 = 0.f;
  int myposA = 0;
  if (lg < 9) {
    int tap = lg;
    int py = pl >> 3, pxx = pl & 7;
    int h = h0 + py, w = w0 + pxx;
    int hw = h * W_ + w;
    const float* p0 = offp3 + (size_t)b * NOFF * HW_ + hw;
    const float* p1 = p0 + (size_t)B_ * NOFF * HW_;
    const float* p2 = p1 + (size_t)B_ * NOFF * HW_;
    int t3 = tap / 3;
    int ky = t3 - 1, kx = tap - t3 * 3 - 1;
    size_t ody = (size_t)(2 * tap) * HW_;
    size_t odx = ody + HW_;
    float dyv = p0[ody] + p1[ody] + p2[ody];
    float dxv = p0[odx] + p1[odx] + p2[odx];
    dyv = fminf(fmaxf(dyv, -1.f), 1.f);
    dxv = fminf(fmaxf(dxv, -1.f), 1.f);
    float ys = (float)(h + ky) + dyv;
    float xs = (float)(w + kx) + dxv;
    float y0f = floorf(ys), x0f = floorf(xs);
    float tyf = ys - y0f, txf = xs - x0f;
    int y0 = (int)y0f, x0 = (int)x0f;
    float fy0 = ((unsigned)y0 < (unsigned)H_) ? 1.f : 0.f;
    float fy1 = ((unsigned)(y0 + 1) < (unsigned)H_) ? 1.f : 0.f;
    float fx0 = ((unsigned)x0 < (unsigned)W_) ? 1.f : 0.f;
    float fx1 = ((unsigned)(x0 + 1) < (unsigned)W_) ? 1.f : 0.f;
    float omty = 1.f - tyf, omtx = 1.f - txf;
    myw0 = omty * omtx * fy0 * fx0;
    myw1 = omty * txf * fy0 * fx1;
    myw2 = tyf * omtx * fy1 * fx0;
    myw3 = tyf * txf * fy1 * fx1;
    myposA = (y0 - (h0 - 2)) * 13 + (x0 - (w0 - 2));
  }

  // ---- halo staging (independent of weight calc; loads overlap) ----
  uint4* halu4 = (uint4*)hal;
  const uint4* xu4 = (const uint4*)xt;
#pragma unroll
  for (int i = 0; i < 6; ++i) {
    int u = i * 512 + tid;            // 117 pos x 24 uint4 = 2808
    if (u < 2808) {
      int pos = u / 24;
      int ly = pos / 13, lx = pos - ly * 13;
      int gy = h0 - 2 + ly, gx = w0 - 2 + lx;
      uint4 v = {0u, 0u, 0u, 0u};
      if ((unsigned)gy < (unsigned)H_ && (unsigned)gx < (unsigned)W_)
        v = xu4[((size_t)b * HW_ + gy * W_ + gx) * 24 + (u - pos * 24)];
      halu4[u] = v;                   // linear
    }
  }
  __syncthreads();

  // ---- blend phase: weights broadcast from lane (pixelbase+tap) ----
  f32x2 acc2[6];
#pragma unroll
  for (int j = 0; j < 6; ++j) acc2[j] = (f32x2){0.f, 0.f};

#pragma unroll
  for (int tap = 0; tap < 9; ++tap) {
    f32x4 w4;
    w4.x = __shfl(myw0, tap, 16);
    w4.y = __shfl(myw1, tap, 16);
    w4.z = __shfl(myw2, tap, 16);
    w4.w = __shfl(myw3, tap, 16);
    int posA = __shfl(myposA, tap, 16);
    const unsigned short* base = hal + posA * 192 + co0;
#pragma unroll
    for (int rep = 0; rep < 3; ++rep) {
      int co = rep * 64;
      uint2 u00 = *(const uint2*)(base + co);
      uint2 u01 = *(const uint2*)(base + 192 + co);
      uint2 u10 = *(const uint2*)(base + 13 * 192 + co);
      uint2 u11 = *(const uint2*)(base + 14 * 192 + co);
      f32x4 dw = *(const f32x4*)&dcnT_g[tap * C_ + co0 + co];
      f32x2 v00l = (f32x2){bflo(u00.x), bfhi(u00.x)};
      f32x2 v01l = (f32x2){bflo(u01.x), bfhi(u01.x)};
      f32x2 v10l = (f32x2){bflo(u10.x), bfhi(u10.x)};
      f32x2 v11l = (f32x2){bflo(u11.x), bfhi(u11.x)};
      f32x2 v00h = (f32x2){bflo(u00.y), bfhi(u00.y)};
      f32x2 v01h = (f32x2){bflo(u01.y), bfhi(u01.y)};
      f32x2 v10h = (f32x2){bflo(u10.y), bfhi(u10.y)};
      f32x2 v11h = (f32x2){bflo(u11.y), bfhi(u11.y)};
      f32x2 sl = v00l * w4.x + v01l * w4.y + v10l * w4.z + v11l * w4.w;
      f32x2 sh = v00h * w4.x + v01h * w4.y + v10h * w4.z + v11h * w4.w;
      acc2[rep * 2 + 0] += sl * (f32x2){dw.x, dw.y};
      acc2[rep * 2 + 1] += sh * (f32x2){dw.z, dw.w};
    }
  }

  // all hal reads done (accumulators in registers) -> safe to overwrite
  __syncthreads();

  {  // write y1 tile into bsm (= first 12 KB of hal), swizzled
    char* sbase = (char*)hal;
    int psw = (pl & 7) << 4;
#pragma unroll
    for (int rep = 0; rep < 3; ++rep) {
      uint2 pk;
      pk.x = (unsigned)f2bf(acc2[rep * 2][0]) | ((unsigned)f2bf(acc2[rep * 2][1]) << 16);
      pk.y = (unsigned)f2bf(acc2[rep * 2 + 1][0]) | ((unsigned)f2bf(acc2[rep * 2 + 1][1]) << 16);
      *(uint2*)(sbase + pl * 384 + ((lg * 8 + rep * 128) ^ psw)) = pk;
    }
  }
  __syncthreads();

  // ---- GEMM phase: 8 waves x 3 m-frags x 2 n-frags over K=192 ----
  {
    const char* sbase = (const char*)hal;
    int wid = tid >> 6;
    int lane = tid & 63;
    int col = lane & 15;
    int kg = lane >> 4;

#pragma unroll 1
    for (int mi = 0; mi < 3; ++mi) {
      int m0 = (wid * 3 + mi) * 16;
      f32x4 acc[2];
      acc[0] = (f32x4){0.f, 0.f, 0.f, 0.f};
      acc[1] = (f32x4){0.f, 0.f, 0.f, 0.f};

#pragma unroll
      for (int k0 = 0; k0 < C_; k0 += 32) {
        short8v a = *(const short8v*)(wtb + (size_t)(m0 + col) * C_ + k0 + kg * 8);
#pragma unroll
        for (int nf = 0; nf < 2; ++nf) {
          int brow = nf * 16 + col;
          int kb = (k0 + kg * 8) * 2;
          short8v bfr = *(const short8v*)(sbase + brow * 384 + (kb ^ ((brow & 7) << 4)));
          acc[nf] = __builtin_amdgcn_mfma_f32_16x16x32_bf16(a, bfr, acc[nf], 0, 0, 0);
        }
      }

#pragma unroll
      for (int nf = 0; nf < 2; ++nf) {
        int px = nf * 16 + col;       // tile pixel 0..31
        int hw = (h0 + (px >> 3)) * W_ + w0 + (px & 7);
#pragma unroll
        for (int reg = 0; reg < 4; ++reg) {
          int o = m0 + kg * 4 + reg;
          float a = acc[nf][reg];
          float r = a * fminf(fmaxf(a + 3.f, 0.f), 6.f) * (1.f / 6.f);
          out[((size_t)b * O_ + o) * HW_ + hw] = r;
        }
      }
    }
  }
}

extern "C" void kernel_launch(void* const* d_in, const int* in_sizes, int n_in,
                              void* d_out, int out_size, void* d_ws, size_t ws_size,
                              hipStream_t stream) {
  const float* x = (const float*)d_in[0];
  const float* og_dw = (const float*)d_in[1];
  const float* og_pw = (const float*)d_in[2];
  const float* dcn_w = (const float*)d_in[3];
  const float* pw_w = (const float*)d_in[4];
  float* out = (float*)d_out;

  float* ws = (float*)d_ws;
  float* offp3 = ws;                                     // 3*B*18*HW f32
  float* dcnT_g = offp3 + 3 * (size_t)B_ * NOFF * HW_;   // 9*C f32
  unsigned short* wtb = (unsigned short*)(dcnT_g + 9 * C_);  // O*C bf16
  unsigned short* x_t = wtb + (size_t)O_ * C_;           // NPIX*C bf16
  unsigned short* w2b = x_t + (size_t)NPIX * C_;         // 32*1728 bf16

  k_xtp<<<dim3(HW_ / 64, B_), TPB, 0, stream>>>(x, og_dw, og_pw, pw_w, dcn_w,
                                                x_t, wtb, w2b, dcnT_g);
  k_off2s<<<dim3(W_ / 8, H_ / 8, B_ * 3), TPB, 0, stream>>>(x_t, w2b, offp3);
  k_dfg4<<<196 * 4 * B_ / 8, 512, 0, stream>>>(x_t, offp3, dcnT_g, wtb, out);
}

// Round 28
// 75.544 us; speedup vs baseline: 1.0228x; 1.0228x over previous
//
#include <hip/hip_runtime.h>
#include <hip/hip_fp16.h>

#define TPB 256
constexpr int B_ = 8, C_ = 192, H_ = 56, W_ = 56, O_ = 384;
constexpr int HW_ = H_ * W_;          // 3136
constexpr int NOFF = 18;              // 9 taps * 2 (dy,dx)
constexpr int NPIX = B_ * HW_;        // 25088
constexpr int K2 = 9 * C_;            // 1728 combined-conv K

typedef __attribute__((ext_vector_type(8))) short short8v;
typedef __attribute__((ext_vector_type(4))) float f32x4;
typedef __attribute__((ext_vector_type(2))) float f32x2;

__device__ inline unsigned short f2bf(float f) {
  unsigned u = __builtin_bit_cast(unsigned, f);
  unsigned r = (u + 0x7fffu + ((u >> 16) & 1u)) >> 16;
  return (unsigned short)r;
}
__device__ inline float bflo(unsigned u) {
  return __builtin_bit_cast(float, u << 16);
}
__device__ inline float bfhi(unsigned u) {
  return __builtin_bit_cast(float, u & 0xffff0000u);
}

// ---- K_XTP: x transpose->bf16 AND all weight prep in one launch ----------
__global__ __launch_bounds__(TPB) void k_xtp(const float* __restrict__ x,
                                             const float* __restrict__ og_dw,
                                             const float* __restrict__ og_pw,
                                             const float* __restrict__ pw,
                                             const float* __restrict__ dcn,
                                             unsigned short* __restrict__ xt,
                                             unsigned short* __restrict__ wtb,
                                             unsigned short* __restrict__ w2b,
                                             float* __restrict__ dcnT_g) {
  __shared__ unsigned short tile[64 * 198];
  int tid = threadIdx.x;
  int P0 = blockIdx.x * 64;
  int b = blockIdx.y;

  int gid = (blockIdx.y * 49 + blockIdx.x) * TPB + tid;
#pragma unroll
  for (int it = 0; it < 2; ++it) {
    int i = gid + it * (49 * 8 * TPB);
    if (i < O_ * C_) {
      wtb[i] = f2bf(pw[i]);
    } else if (i < O_ * C_ + 32 * K2) {
      int j = i - O_ * C_;
      int o = j / K2, k = j - o * K2;
      int tap = k / C_, c = k - tap * C_;
      float v = 0.f;
      if (o < NOFF) v = og_pw[o * C_ + c] * og_dw[c * 9 + tap];
      w2b[j] = f2bf(v);
    } else if (i < O_ * C_ + 32 * K2 + 9 * C_) {
      int j2 = i - O_ * C_ - 32 * K2;
      int k = j2 / C_, c = j2 - k * C_;
      dcnT_g[j2] = dcn[c * 9 + k];
    }
  }

#pragma unroll
  for (int i = 0; i < 48; ++i) {
    int idx = i * TPB + tid;
    int px = idx & 63;
    int c = idx >> 6;
    float v = x[((size_t)(b * C_ + c)) * HW_ + P0 + px];
    tile[px * 198 + c] = f2bf(v);
  }
  __syncthreads();
  unsigned* xtu = (unsigned*)xt;
#pragma unroll
  for (int i = 0; i < 24; ++i) {
    int d = i * TPB + tid;
    int px = d / 96;
    int c2 = d - px * 96;
    unsigned v = *(const unsigned*)&tile[px * 198 + c2 * 2];
    xtu[((size_t)b * HW_ + P0 + px) * 96 + c2] = v;
  }
}

// ---- K_OFF2s: offset conv, K-split by tap-row; batch->XCD swizzled -------
__global__ __launch_bounds__(TPB) void k_off2s(const unsigned short* __restrict__ xt,
                                               const unsigned short* __restrict__ w2b,
                                               float* __restrict__ offp3) {
  __shared__ __align__(16) unsigned short hal[80 * 192];  // 30.7 KB
  int tid = threadIdx.x;
  int w0 = blockIdx.x * 8;
  int h0 = blockIdx.y * 8;
  int bz = blockIdx.z;
  int b = bz & 7;
  int s = bz >> 3;
  int dy = s - 1;

  char* sb = (char*)hal;
  const uint4* xu4 = (const uint4*)xt;
#pragma unroll
  for (int i = 0; i < 8; ++i) {
    int u = i * TPB + tid;
    if (u < 1920) {
      int pos = u / 24, c4 = u - pos * 24;
      int ry = pos / 10;
      int gy = h0 + ry + dy;
      int gx = w0 - 1 + (pos - ry * 10);
      uint4 v = {0u, 0u, 0u, 0u};
      if ((unsigned)gy < (unsigned)H_ && (unsigned)gx < (unsigned)W_)
        v = xu4[((size_t)b * HW_ + gy * W_ + gx) * 24 + c4];
      *(uint4*)(sb + pos * 384 + ((c4 * 16) ^ ((pos & 7) << 4))) = v;
    }
  }
  __syncthreads();

  int wid = tid >> 6;
  int lane = tid & 63;
  int col = lane & 15;
  int kg = lane >> 4;
  int gpx = wid * 16 + col;
  int py = gpx >> 3, px_ = gpx & 7;

  f32x4 acc0 = (f32x4){0.f, 0.f, 0.f, 0.f};
  f32x4 acc1 = (f32x4){0.f, 0.f, 0.f, 0.f};

#pragma unroll
  for (int j = 0; j < 3; ++j) {
    int tap = 3 * s + j;
    int pos = py * 10 + px_ + j;
    int pbase = pos * 384;
    int psw = (pos & 7) << 4;
    const unsigned short* wrow = w2b + tap * C_ + kg * 8;
#pragma unroll
    for (int cs = 0; cs < 6; ++cs) {
      short8v bfrag = *(const short8v*)(sb + pbase + ((cs * 64 + kg * 16) ^ psw));
      short8v a0 = *(const short8v*)(wrow + cs * 32 + (size_t)col * K2);
      short8v a1 = *(const short8v*)(wrow + cs * 32 + (size_t)(16 + col) * K2);
      acc0 = __builtin_amdgcn_mfma_f32_16x16x32_bf16(a0, bfrag, acc0, 0, 0, 0);
      acc1 = __builtin_amdgcn_mfma_f32_16x16x32_bf16(a1, bfrag, acc1, 0, 0, 0);
    }
  }

  float* ob = offp3 + (size_t)(s * B_ + b) * NOFF * HW_ + (h0 + py) * W_ + w0 + px_;
#pragma unroll
  for (int reg = 0; reg < 4; ++reg) {
    int o0 = kg * 4 + reg;
    ob[(size_t)o0 * HW_] = acc0[reg];
    int o1 = 16 + kg * 4 + reg;
    if (o1 < NOFF) ob[(size_t)o1 * HW_] = acc1[reg];
  }
}

// ---- K_DFGEMM: fused deform+gemm, 8x4 tile, bsm ALIASED onto hal ---------
// R22/R26 configuration (session best, 75.8 us). LDS 50.7 KB; 16-lane/px
// uint2 blend (zero bank conflicts); batch->XCD swizzle.
__global__ __launch_bounds__(512, 4) void k_dfgemm(const unsigned short* __restrict__ xt,
                                                   const float* __restrict__ offp3,
                                                   const float* __restrict__ dcnT_g,
                                                   const unsigned short* __restrict__ wtb,
                                                   float* __restrict__ out) {
  __shared__ __align__(16) unsigned short hal[117 * 192];  // 44.9 KB; bsm aliases first 12 KB
  __shared__ __align__(16) f32x4 w4tab[288];               // 4.6 KB
  __shared__ int postab[288];                              // 1.2 KB
  int tid = threadIdx.x;
  int bid = blockIdx.x;
  int b = bid & 7;                    // XCD-locality: batch b -> XCD b
  int tile = bid >> 3;                // 0..97
  int ty = tile / 7;
  int h0 = ty * 4;
  int w0 = (tile - ty * 7) * 8;

  uint4* halu4 = (uint4*)hal;
  const uint4* xu4 = (const uint4*)xt;
#pragma unroll
  for (int i = 0; i < 6; ++i) {
    int u = i * 512 + tid;            // 117 pos x 24 uint4 = 2808
    if (u < 2808) {
      int pos = u / 24;
      int ly = pos / 13, lx = pos - ly * 13;
      int gy = h0 - 2 + ly, gx = w0 - 2 + lx;
      uint4 v = {0u, 0u, 0u, 0u};
      if ((unsigned)gy < (unsigned)H_ && (unsigned)gx < (unsigned)W_)
        v = xu4[((size_t)b * HW_ + gy * W_ + gx) * 24 + (u - pos * 24)];
      halu4[u] = v;                   // linear
    }
  }

  if (tid < 288) {                    // 32 px x 9 taps
    int pxl = tid / 9, tap = tid - pxl * 9;
    int py = pxl >> 3, pxx = pxl & 7;
    int h = h0 + py, w = w0 + pxx;
    int hw = h * W_ + w;
    const float* p0 = offp3 + (size_t)b * NOFF * HW_ + hw;
    const float* p1 = p0 + (size_t)B_ * NOFF * HW_;
    const float* p2 = p1 + (size_t)B_ * NOFF * HW_;
    int t3 = tap / 3;
    int ky = t3 - 1, kx = tap - t3 * 3 - 1;
    size_t ody = (size_t)(2 * tap) * HW_;
    size_t odx = ody + HW_;
    float dyv = p0[ody] + p1[ody] + p2[ody];
    float dxv = p0[odx] + p1[odx] + p2[odx];
    dyv = fminf(fmaxf(dyv, -1.f), 1.f);
    dxv = fminf(fmaxf(dxv, -1.f), 1.f);
    float ys = (float)(h + ky) + dyv;
    float xs = (float)(w + kx) + dxv;
    float y0f = floorf(ys), x0f = floorf(xs);
    float tyf = ys - y0f, txf = xs - x0f;
    int y0 = (int)y0f, x0 = (int)x0f;
    float fy0 = ((unsigned)y0 < (unsigned)H_) ? 1.f : 0.f;
    float fy1 = ((unsigned)(y0 + 1) < (unsigned)H_) ? 1.f : 0.f;
    float fx0 = ((unsigned)x0 < (unsigned)W_) ? 1.f : 0.f;
    float fx1 = ((unsigned)(x0 + 1) < (unsigned)W_) ? 1.f : 0.f;
    float omty = 1.f - tyf, omtx = 1.f - txf;
    f32x4 w4;
    w4.x = omty * omtx * fy0 * fx0;
    w4.y = omty * txf * fy0 * fx1;
    w4.z = tyf * omtx * fy1 * fx0;
    w4.w = tyf * txf * fy1 * fx1;
    w4tab[tid] = w4;
    postab[tid] = (y0 - (h0 - 2)) * 13 + (x0 - (w0 - 2));
  }
  __syncthreads();

  f32x2 acc2[6];
#pragma unroll
  for (int j = 0; j < 6; ++j) acc2[j] = (f32x2){0.f, 0.f};
  int pl = tid >> 4;                  // 0..31: local pixel
  int lg = tid & 15;
  int co0 = lg * 4;

#pragma unroll
  for (int tap = 0; tap < 9; ++tap) {
    f32x4 w4 = w4tab[pl * 9 + tap];
    int posA = postab[pl * 9 + tap];
    const unsigned short* base = hal + posA * 192 + co0;
#pragma unroll
    for (int rep = 0; rep < 3; ++rep) {
      int co = rep * 64;
      uint2 u00 = *(const uint2*)(base + co);
      uint2 u01 = *(const uint2*)(base + 192 + co);
      uint2 u10 = *(const uint2*)(base + 13 * 192 + co);
      uint2 u11 = *(const uint2*)(base + 14 * 192 + co);
      f32x4 dw = *(const f32x4*)&dcnT_g[tap * C_ + co0 + co];
      f32x2 v00l = (f32x2){bflo(u00.x), bfhi(u00.x)};
      f32x2 v01l = (f32x2){bflo(u01.x), bfhi(u01.x)};
      f32x2 v10l = (f32x2){bflo(u10.x), bfhi(u10.x)};
      f32x2 v11l = (f32x2){bflo(u11.x), bfhi(u11.x)};
      f32x2 v00h = (f32x2){bflo(u00.y), bfhi(u00.y)};
      f32x2 v01h = (f32x2){bflo(u01.y), bfhi(u01.y)};
      f32x2 v10h = (f32x2){bflo(u10.y), bfhi(u10.y)};
      f32x2 v11h = (f32x2){bflo(u11.y), bfhi(u11.y)};
      f32x2 sl = v00l * w4.x + v01l * w4.y + v10l * w4.z + v11l * w4.w;
      f32x2 sh = v00h * w4.x + v01h * w4.y + v10h * w4.z + v11h * w4.w;
      acc2[rep * 2 + 0] += sl * (f32x2){dw.x, dw.y};
      acc2[rep * 2 + 1] += sh * (f32x2){dw.z, dw.w};
    }
  }

  // all hal reads done (accumulators in registers) -> safe to overwrite
  __syncthreads();

  {  // write y1 tile into bsm (= first 12 KB of hal), swizzled
    char* sbase = (char*)hal;
    int psw = (pl & 7) << 4;
#pragma unroll
    for (int rep = 0; rep < 3; ++rep) {
      uint2 pk;
      pk.x = (unsigned)f2bf(acc2[rep * 2][0]) | ((unsigned)f2bf(acc2[rep * 2][1]) << 16);
      pk.y = (unsigned)f2bf(acc2[rep * 2 + 1][0]) | ((unsigned)f2bf(acc2[rep * 2 + 1][1]) << 16);
      *(uint2*)(sbase + pl * 384 + ((lg * 8 + rep * 128) ^ psw)) = pk;
    }
  }
  __syncthreads();

  // ---- GEMM phase: 8 waves x 3 m-frags x 2 n-frags over K=192 ----
  {
    const char* sbase = (const char*)hal;
    int wid = tid >> 6;
    int lane = tid & 63;
    int col = lane & 15;
    int kg = lane >> 4;

#pragma unroll 1
    for (int mi = 0; mi < 3; ++mi) {
      int m0 = (wid * 3 + mi) * 16;
      f32x4 acc[2];
      acc[0] = (f32x4){0.f, 0.f, 0.f, 0.f};
      acc[1] = (f32x4){0.f, 0.f, 0.f, 0.f};

#pragma unroll
      for (int k0 = 0; k0 < C_; k0 += 32) {
        short8v a = *(const short8v*)(wtb + (size_t)(m0 + col) * C_ + k0 + kg * 8);
#pragma unroll
        for (int nf = 0; nf < 2; ++nf) {
          int brow = nf * 16 + col;
          int kb = (k0 + kg * 8) * 2;
          short8v bfr = *(const short8v*)(sbase + brow * 384 + (kb ^ ((brow & 7) << 4)));
          acc[nf] = __builtin_amdgcn_mfma_f32_16x16x32_bf16(a, bfr, acc[nf], 0, 0, 0);
        }
      }

#pragma unroll
      for (int nf = 0; nf < 2; ++nf) {
        int px = nf * 16 + col;       // tile pixel 0..31
        int hw = (h0 + (px >> 3)) * W_ + w0 + (px & 7);
#pragma unroll
        for (int reg = 0; reg < 4; ++reg) {
          int o = m0 + kg * 4 + reg;
          float a = acc[nf][reg];
          float r = a * fminf(fmaxf(a + 3.f, 0.f), 6.f) * (1.f / 6.f);
          out[((size_t)b * O_ + o) * HW_ + hw] = r;
        }
      }
    }
  }
}

extern "C" void kernel_launch(void* const* d_in, const int* in_sizes, int n_in,
                              void* d_out, int out_size, void* d_ws, size_t ws_size,
                              hipStream_t stream) {
  const float* x = (const float*)d_in[0];
  const float* og_dw = (const float*)d_in[1];
  const float* og_pw = (const float*)d_in[2];
  const float* dcn_w = (const float*)d_in[3];
  const float* pw_w = (const float*)d_in[4];
  float* out = (float*)d_out;

  float* ws = (float*)d_ws;
  float* offp3 = ws;                                     // 3*B*18*HW f32
  float* dcnT_g = offp3 + 3 * (size_t)B_ * NOFF * HW_;   // 9*C f32
  unsigned short* wtb = (unsigned short*)(dcnT_g + 9 * C_);  // O*C bf16
  unsigned short* x_t = wtb + (size_t)O_ * C_;           // NPIX*C bf16
  unsigned short* w2b = x_t + (size_t)NPIX * C_;         // 32*1728 bf16

  k_xtp<<<dim3(HW_ / 64, B_), TPB, 0, stream>>>(x, og_dw, og_pw, pw_w, dcn_w,
                                                x_t, wtb, w2b, dcnT_g);
  k_off2s<<<dim3(W_ / 8, H_ / 8, B_ * 3), TPB, 0, stream>>>(x_t, w2b, offp3);
  k_dfgemm<<<196 * 4 * B_ / 8, 512, 0, stream>>>(x_t, offp3, dcnT_g, wtb, out);
}